// Round 9
// baseline (829.051 us; speedup 1.0000x reference)
//
#include <hip/hip_runtime.h>

typedef __bf16 bf16;
typedef bf16 bf16x8 __attribute__((ext_vector_type(8)));
typedef bf16 bf16x4 __attribute__((ext_vector_type(4)));
typedef bf16 bf16x2 __attribute__((ext_vector_type(2)));
typedef float floatx4 __attribute__((ext_vector_type(4)));

#define MFMA __builtin_amdgcn_mfma_f32_16x16x32_bf16

__device__ __forceinline__ float bfhi_f(unsigned u) {
  const unsigned x = u << 16;
  return __builtin_bit_cast(float, x);
}
__device__ __forceinline__ float bflo_f(unsigned u) {
  const unsigned x = u & 0xffff0000u;
  return __builtin_bit_cast(float, x);
}

// ---------------- setup kernels ----------------

__global__ void hist_kernel(const int* __restrict__ ei, int* __restrict__ cnt, int E) {
  int e = blockIdx.x * blockDim.x + threadIdx.x;
  if (e < E) atomicAdd(&cnt[ei[E + e]], 1);
}

__global__ void gcnt_kernel(const int* __restrict__ batch, int* __restrict__ gcnt,
                            int N, int B) {
  const int b = threadIdx.x;
  if (b >= B) return;
  auto lb = [&](int v) {
    int lo = 0, hi = N;
    while (lo < hi) {
      const int mid = (lo + hi) >> 1;
      if (batch[mid] < v) lo = mid + 1; else hi = mid;
    }
    return lo;
  };
  gcnt[b] = lb(b + 1) - lb(b);
}

__global__ void scan1_kernel(const int* __restrict__ cnt, int* __restrict__ colptr,
                             int* __restrict__ rctr, int* __restrict__ btot, int n) {
  __shared__ int sd[256];
  const int tid = threadIdx.x;
  const int i0 = blockIdx.x * 2048 + tid * 8;
  int v[8];
  int tot = 0;
#pragma unroll
  for (int j = 0; j < 8; ++j) {
    const int i = i0 + j;
    v[j] = (i < n) ? cnt[i] : 0;
    tot += v[j];
  }
  sd[tid] = tot;
  __syncthreads();
  for (int off = 1; off < 256; off <<= 1) {
    const int t = (tid >= off) ? sd[tid - off] : 0;
    __syncthreads();
    sd[tid] += t;
    __syncthreads();
  }
  int excl = sd[tid] - tot;
#pragma unroll
  for (int j = 0; j < 8; ++j) {
    const int i = i0 + j;
    if (i < n) { colptr[i] = excl; rctr[i] = excl; }
    excl += v[j];
  }
  if (tid == 255) btot[blockIdx.x] = sd[255];
}

__global__ void scan2_kernel(int* __restrict__ colptr, int* __restrict__ rctr,
                             const int* __restrict__ btot, int n) {
  __shared__ int off_s;
  const int tid = threadIdx.x;
  if (blockIdx.x == 0) return;
  if (tid == 0) {
    int o = 0;
    for (int j = 0; j < (int)blockIdx.x; ++j) o += btot[j];
    off_s = o;
  }
  __syncthreads();
  const int off = off_s;
  const int i0 = blockIdx.x * 2048 + tid * 8;
#pragma unroll
  for (int j = 0; j < 8; ++j) {
    const int i = i0 + j;
    if (i < n) { colptr[i] += off; rctr[i] += off; }
  }
}

__global__ void place_kernel(const int* __restrict__ ei, int* __restrict__ rctr,
                             int* __restrict__ esrow, int E) {
  int e = blockIdx.x * blockDim.x + threadIdx.x;
  if (e >= E) return;
  const int r = ei[e];
  const int c = ei[E + e];
  const int p = atomicAdd(&rctr[c], 1);
  esrow[p] = r;
}

// transpose+split: src [L][Ksrc][H] fp32 (first K rows) -> dst [L][2][H][K] bf16
__global__ void wsplit_kernel(const float* __restrict__ src, bf16* __restrict__ dst,
                              int Ksrc, int K, int HH) {
  const int l = blockIdx.y;
  const int gid = blockIdx.x * blockDim.x + threadIdx.x;
  if (gid >= K * HH) return;
  const int h = gid / K, k = gid - h * K;
  const float v = src[(size_t)l * Ksrc * HH + (size_t)k * HH + h];
  const bf16 hi = (bf16)v;
  const bf16 lo = (bf16)(v - (float)hi);
  bf16* d = dst + (size_t)l * 2 * K * HH;
  d[(size_t)h * K + k] = hi;
  d[(size_t)K * HH + (size_t)h * K + k] = lo;
}

__global__ void xsplit_kernel(const float* __restrict__ x, bf16* __restrict__ xhi,
                              bf16* __restrict__ xlo, int n4) {
  const int i = blockIdx.x * 256 + threadIdx.x;
  if (i >= n4) return;
  const float4 v = ((const float4*)x)[i];
  bf16x4 h, l;
  const float vv[4] = {v.x, v.y, v.z, v.w};
#pragma unroll
  for (int r = 0; r < 4; ++r) {
    h[r] = (bf16)vv[r];
    l[r] = (bf16)(vv[r] - (float)h[r]);
  }
  *(bf16x4*)&xhi[(size_t)i * 4] = h;
  *(bf16x4*)&xlo[(size_t)i * 4] = l;
}

// ---------------- layer-0 edge MLP per node (8-wave, TLP-hiding) ---------
__global__ __launch_bounds__(512, 6)
void pnode_mfma(const bf16* __restrict__ xh, const bf16* __restrict__ xl,
                const bf16* __restrict__ w1t, const float* __restrict__ b1,
                const bf16* __restrict__ w2t, const float* __restrict__ b2,
                bf16* __restrict__ P, int N) {
  __shared__ __align__(16) bf16 R[2 * 64 * 136];

  const int tid = threadIdx.x;
  const int n0 = blockIdx.x * 64;
  const int wave = tid >> 6, lane = tid & 63, q = lane >> 4, lr = lane & 15;
  const int hbase = wave * 16;

  int nn[4];
#pragma unroll
  for (int nt = 0; nt < 4; ++nt) {
    int n = n0 + nt * 16 + lr;
    nn[nt] = (n > N - 1) ? (N - 1) : n;
  }

  const floatx4 zz = {0.f, 0.f, 0.f, 0.f};
  floatx4 acc[4];
#pragma unroll
  for (int nt = 0; nt < 4; ++nt) acc[nt] = zz;

  // GEMM1: K=128
#pragma unroll
  for (int kc = 0; kc < 4; ++kc) {
    const bf16* wp = w1t + (size_t)(hbase + lr) * 128 + kc * 32 + q * 8;
    const bf16x8 ah = *(const bf16x8*)wp;
    const bf16x8 al = *(const bf16x8*)(wp + 16384);
    bf16x8 bh[4], bl[4];
#pragma unroll
    for (int nt = 0; nt < 4; ++nt) {
      const size_t off = (size_t)nn[nt] * 128 + kc * 32 + q * 8;
      bh[nt] = *(const bf16x8*)(xh + off);
      bl[nt] = *(const bf16x8*)(xl + off);
    }
#pragma unroll
    for (int nt = 0; nt < 4; ++nt) {
      acc[nt] = MFMA(ah, bh[nt], acc[nt], 0, 0, 0);
      acc[nt] = MFMA(al, bh[nt], acc[nt], 0, 0, 0);
      acc[nt] = MFMA(ah, bl[nt], acc[nt], 0, 0, 0);
    }
  }

  // epilogue 1: bias+relu -> H1 hi/lo
  {
    const int h0 = hbase + q * 4;
    const float* bp = &b1[h0];
#pragma unroll
    for (int nt = 0; nt < 4; ++nt) {
      const int e = nt * 16 + lr;
      bf16x4 hh, ll;
#pragma unroll
      for (int r = 0; r < 4; ++r) {
        const float v = fmaxf(acc[nt][r] + bp[r], 0.f);
        hh[r] = (bf16)v;
        ll[r] = (bf16)(v - (float)hh[r]);
      }
      *(bf16x4*)&R[e * 136 + h0] = hh;
      *(bf16x4*)&R[64 * 136 + e * 136 + h0] = ll;
      acc[nt] = zz;
    }
  }
  __syncthreads();

  // GEMM2
#pragma unroll
  for (int ks = 0; ks < 4; ++ks) {
    const bf16* wp = w2t + (size_t)(hbase + lr) * 128 + ks * 32 + q * 8;
    const bf16x8 ah = *(const bf16x8*)wp;
    const bf16x8 al = *(const bf16x8*)(wp + 16384);
    bf16x8 b2h[4], b2l[4];
#pragma unroll
    for (int nt = 0; nt < 4; ++nt) {
      const bf16* hp = &R[(nt * 16 + lr) * 136 + ks * 32 + q * 8];
      b2h[nt] = *(const bf16x8*)hp;
      b2l[nt] = *(const bf16x8*)(hp + 64 * 136);
    }
#pragma unroll
    for (int nt = 0; nt < 4; ++nt) {
      acc[nt] = MFMA(ah, b2h[nt], acc[nt], 0, 0, 0);
      acc[nt] = MFMA(al, b2h[nt], acc[nt], 0, 0, 0);
      acc[nt] = MFMA(ah, b2l[nt], acc[nt], 0, 0, 0);
    }
  }
  __syncthreads();

  // epilogue 2: +b2 -> tile, coalesced store
  {
    const int f0 = hbase + q * 4;
    const float* bp = &b2[f0];
#pragma unroll
    for (int nt = 0; nt < 4; ++nt) {
      const int e = nt * 16 + lr;
      bf16x4 o;
#pragma unroll
      for (int r = 0; r < 4; ++r) o[r] = (bf16)(acc[nt][r] + bp[r]);
      *(bf16x4*)&R[e * 136 + f0] = o;
    }
  }
  __syncthreads();
#pragma unroll
  for (int it = 0; it < 2; ++it) {
    const int idx = it * 512 + tid;
    const int row = idx >> 4;
    const int f8 = (idx & 15) * 8;
    const int n = n0 + row;
    if (n < N)
      *(bf16x8*)&P[(size_t)n * 128 + f8] = *(const bf16x8*)&R[row * 136 + f8];
  }
}

// ---------------- CSR mean-aggregate: one WAVE per column, bf16x2/lane ---
// each gather instruction pulls the full 256B row once (vs 2x128B before)
__global__ __launch_bounds__(256, 8)
void agg_csr(const bf16* __restrict__ P, const int* __restrict__ colptr,
             const int* __restrict__ esrow,
             bf16* __restrict__ aggh, bf16* __restrict__ aggl, int N, int E) {
  const int lane = threadIdx.x & 63;
  const int c = blockIdx.x * 4 + (threadIdx.x >> 6);
  if (c >= N) return;
  const int beg = colptr[c];
  const int end = (c == N - 1) ? E : colptr[c + 1];
  float s0[4] = {0.f, 0.f, 0.f, 0.f};
  float s1[4] = {0.f, 0.f, 0.f, 0.f};
  int e = beg;
  for (; e + 8 <= end; e += 8) {
    int r[8];
#pragma unroll
    for (int j = 0; j < 8; ++j) r[j] = esrow[e + j];
    unsigned v[8];
#pragma unroll
    for (int j = 0; j < 8; ++j)
      v[j] = *(const unsigned*)&P[(size_t)r[j] * 128 + lane * 2];
#pragma unroll
    for (int j = 0; j < 8; ++j) {
      s0[j & 3] += bfhi_f(v[j]);
      s1[j & 3] += bflo_f(v[j]);
    }
  }
  const int rem = end - e;
  if (rem > 0) {
    int r[8];
#pragma unroll
    for (int j = 0; j < 8; ++j) r[j] = esrow[e + (j < rem ? j : 0)];
    unsigned v[8];
#pragma unroll
    for (int j = 0; j < 8; ++j)
      v[j] = *(const unsigned*)&P[(size_t)r[j] * 128 + lane * 2];
#pragma unroll
    for (int j = 0; j < 8; ++j) {
      if (j < rem) {
        s0[j & 3] += bfhi_f(v[j]);
        s1[j & 3] += bflo_f(v[j]);
      }
    }
  }
  const int cc = end - beg;
  const float inv = 1.f / (float)(cc > 1 ? cc : 1);
  const float v0 = ((s0[0] + s0[1]) + (s0[2] + s0[3])) * inv;
  const float v1 = ((s1[0] + s1[1]) + (s1[2] + s1[3])) * inv;
  bf16x2 h, l;
  h[0] = (bf16)v0;  l[0] = (bf16)(v0 - (float)h[0]);
  h[1] = (bf16)v1;  l[1] = (bf16)(v1 - (float)h[1]);
  *(bf16x2*)&aggh[(size_t)c * 128 + lane * 2] = h;
  *(bf16x2*)&aggl[(size_t)c * 128 + lane * 2] = l;
}

// ---------------- fused node MLP + gsum + next-layer P (8-wave) ----------
__global__ __launch_bounds__(512, 6)
void node_p(bf16* xh, bf16* xl,
            const bf16* __restrict__ aggh, const bf16* __restrict__ aggl,
            const float* __restrict__ UW, const int* __restrict__ batch,
            const bf16* __restrict__ w1t, const bf16* __restrict__ w2t,
            const float* __restrict__ b2,
            const bf16* __restrict__ w1te, const float* __restrict__ b1e,
            const bf16* __restrict__ w2te, const float* __restrict__ b2e,
            bf16* __restrict__ Pout, float* __restrict__ gx,
            float* __restrict__ xout, int write_x, int has_next, int N) {
  __shared__ __align__(16) bf16 R[2 * 64 * 136];   // 34.8 KB, time-shared
  __shared__ int sbatch[64];

  const int tid = threadIdx.x;
  const int n0 = blockIdx.x * 64;
  const int wave = tid >> 6, lane = tid & 63, q = lane >> 4, lr = lane & 15;
  const int hbase = wave * 16;

  if (tid < 64) {
    int n = n0 + tid;
    sbatch[tid] = batch[(n > N - 1) ? (N - 1) : n];
  }

  int nn[4], ub[4];
#pragma unroll
  for (int nt = 0; nt < 4; ++nt) {
    int n = n0 + nt * 16 + lr;
    if (n > N - 1) n = N - 1;
    nn[nt] = n;
    ub[nt] = batch[n];
  }

  floatx4 acc[4];
#pragma unroll
  for (int nt = 0; nt < 4; ++nt)
    acc[nt] = *(const floatx4*)&UW[(size_t)ub[nt] * 128 + hbase + q * 4];

  // GEMM1: K=256 (x hi/lo | agg hi/lo)
#pragma unroll
  for (int kc = 0; kc < 8; ++kc) {
    const bf16* wp = w1t + (size_t)(hbase + lr) * 256 + kc * 32 + q * 8;
    const bf16x8 ah = *(const bf16x8*)wp;
    const bf16x8 al = *(const bf16x8*)(wp + 32768);
    bf16x8 bh[4], bl[4];
#pragma unroll
    for (int nt = 0; nt < 4; ++nt) {
      if (kc < 4) {
        const size_t off = (size_t)nn[nt] * 128 + kc * 32 + q * 8;
        bh[nt] = *(const bf16x8*)(xh + off);
        bl[nt] = *(const bf16x8*)(xl + off);
      } else {
        const size_t off = (size_t)nn[nt] * 128 + (kc - 4) * 32 + q * 8;
        bh[nt] = *(const bf16x8*)(aggh + off);
        bl[nt] = *(const bf16x8*)(aggl + off);
      }
    }
#pragma unroll
    for (int nt = 0; nt < 4; ++nt) {
      acc[nt] = MFMA(ah, bh[nt], acc[nt], 0, 0, 0);
      acc[nt] = MFMA(al, bh[nt], acc[nt], 0, 0, 0);
      acc[nt] = MFMA(ah, bl[nt], acc[nt], 0, 0, 0);
    }
  }

  // epilogue 1: relu (b1 folded in UW) -> H1 hi/lo
  const floatx4 zz = {0.f, 0.f, 0.f, 0.f};
  {
    const int h0 = hbase + q * 4;
#pragma unroll
    for (int nt = 0; nt < 4; ++nt) {
      const int e = nt * 16 + lr;
      bf16x4 hh, ll;
#pragma unroll
      for (int r = 0; r < 4; ++r) {
        const float v = fmaxf(acc[nt][r], 0.f);
        hh[r] = (bf16)v;
        ll[r] = (bf16)(v - (float)hh[r]);
      }
      *(bf16x4*)&R[e * 136 + h0] = hh;
      *(bf16x4*)&R[64 * 136 + e * 136 + h0] = ll;
      acc[nt] = zz;
    }
  }
  __syncthreads();

  // GEMM2
#pragma unroll
  for (int ks = 0; ks < 4; ++ks) {
    const bf16* wp = w2t + (size_t)(hbase + lr) * 128 + ks * 32 + q * 8;
    const bf16x8 ah = *(const bf16x8*)wp;
    const bf16x8 al = *(const bf16x8*)(wp + 16384);
    bf16x8 b2h[4], b2l[4];
#pragma unroll
    for (int nt = 0; nt < 4; ++nt) {
      const bf16* hp = &R[(nt * 16 + lr) * 136 + ks * 32 + q * 8];
      b2h[nt] = *(const bf16x8*)hp;
      b2l[nt] = *(const bf16x8*)(hp + 64 * 136);
    }
#pragma unroll
    for (int nt = 0; nt < 4; ++nt) {
      acc[nt] = MFMA(ah, b2h[nt], acc[nt], 0, 0, 0);
      acc[nt] = MFMA(al, b2h[nt], acc[nt], 0, 0, 0);
      acc[nt] = MFMA(ah, b2l[nt], acc[nt], 0, 0, 0);
    }
  }
  __syncthreads();   // H1 reads done; Xt fp32 [64][132] overlays R

  // epilogue 2: +b2 -> Xt
  float* Xt = (float*)&R[0];
  {
    const int f0 = hbase + q * 4;
    const float* bp = &b2[f0];
#pragma unroll
    for (int nt = 0; nt < 4; ++nt) {
      const int e = nt * 16 + lr;
      const int n = n0 + e;
      float4 o;
      o.x = (n < N) ? acc[nt][0] + bp[0] : 0.f;
      o.y = (n < N) ? acc[nt][1] + bp[1] : 0.f;
      o.z = (n < N) ? acc[nt][2] + bp[2] : 0.f;
      o.w = (n < N) ? acc[nt][3] + bp[3] : 0.f;
      *(float4*)&Xt[e * 132 + f0] = o;
    }
  }
  __syncthreads();

  // coalesced xh/xl stores (next layer), optional xout
  if (has_next) {
#pragma unroll
    for (int it = 0; it < 2; ++it) {
      const int idx = it * 512 + tid;
      const int row = idx >> 4;
      const int f8 = (idx & 15) * 8;
      const int n = n0 + row;
      if (n < N) {
        bf16x8 hh, ll;
#pragma unroll
        for (int j = 0; j < 8; ++j) {
          const float v = Xt[row * 132 + f8 + j];
          hh[j] = (bf16)v;
          ll[j] = (bf16)(v - (float)hh[j]);
        }
        *(bf16x8*)&xh[(size_t)n * 128 + f8] = hh;
        *(bf16x8*)&xl[(size_t)n * 128 + f8] = ll;
      }
    }
  }
  if (write_x) {
#pragma unroll
    for (int it = 0; it < 4; ++it) {
      const int idx = it * 512 + tid;
      const int row = idx >> 5;
      const int f4 = (idx & 31) * 4;
      const int n = n0 + row;
      if (n < N)
        *(float4*)&xout[(size_t)n * 128 + f4] = *(const float4*)&Xt[row * 132 + f4];
    }
  }

  // fused gsum: segmented reduce over 64 sorted-batch nodes (4 groups of 16)
  {
    const int f = tid & 127;
    const int es = (tid >> 7) * 16;
    int cur = sbatch[es];
    float s = 0.f;
    for (int e = es; e < es + 16; ++e) {
      const int b = sbatch[e];
      const float v = Xt[e * 132 + f];
      if (b != cur) {
        atomicAdd(&gx[(size_t)cur * 128 + f], s);
        s = 0.f;
        cur = b;
      }
      s += v;
    }
    atomicAdd(&gx[(size_t)cur * 128 + f], s);
  }

  if (!has_next) return;

  // P phase: Pout = relu(x@W1e+b1e)@W2e+b2e, x from Xt in LDS
#pragma unroll
  for (int nt = 0; nt < 4; ++nt) acc[nt] = zz;

#pragma unroll
  for (int kc = 0; kc < 4; ++kc) {
    const bf16* wp = w1te + (size_t)(hbase + lr) * 128 + kc * 32 + q * 8;
    const bf16x8 ah = *(const bf16x8*)wp;
    const bf16x8 al = *(const bf16x8*)(wp + 16384);
    bf16x8 bh[4], bl[4];
#pragma unroll
    for (int nt = 0; nt < 4; ++nt) {
      const float* xp = &Xt[(nt * 16 + lr) * 132 + kc * 32 + q * 8];
#pragma unroll
      for (int r = 0; r < 8; ++r) {
        const float v = xp[r];
        bh[nt][r] = (bf16)v;
        bl[nt][r] = (bf16)(v - (float)bh[nt][r]);
      }
    }
#pragma unroll
    for (int nt = 0; nt < 4; ++nt) {
      acc[nt] = MFMA(ah, bh[nt], acc[nt], 0, 0, 0);
      acc[nt] = MFMA(al, bh[nt], acc[nt], 0, 0, 0);
      acc[nt] = MFMA(ah, bl[nt], acc[nt], 0, 0, 0);
    }
  }
  __syncthreads();   // Xt reads (incl. gsum) done; H1p overlays R

  // epilogue 1p: +b1e, relu -> H1p hi/lo
  {
    const int h0 = hbase + q * 4;
    const float* bp = &b1e[h0];
#pragma unroll
    for (int nt = 0; nt < 4; ++nt) {
      const int e = nt * 16 + lr;
      bf16x4 hh, ll;
#pragma unroll
      for (int r = 0; r < 4; ++r) {
        const float v = fmaxf(acc[nt][r] + bp[r], 0.f);
        hh[r] = (bf16)v;
        ll[r] = (bf16)(v - (float)hh[r]);
      }
      *(bf16x4*)&R[e * 136 + h0] = hh;
      *(bf16x4*)&R[64 * 136 + e * 136 + h0] = ll;
      acc[nt] = zz;
    }
  }
  __syncthreads();

  // P-GEMM2
#pragma unroll
  for (int ks = 0; ks < 4; ++ks) {
    const bf16* wp = w2te + (size_t)(hbase + lr) * 128 + ks * 32 + q * 8;
    const bf16x8 ah = *(const bf16x8*)wp;
    const bf16x8 al = *(const bf16x8*)(wp + 16384);
    bf16x8 b2h[4], b2l[4];
#pragma unroll
    for (int nt = 0; nt < 4; ++nt) {
      const bf16* hp = &R[(nt * 16 + lr) * 136 + ks * 32 + q * 8];
      b2h[nt] = *(const bf16x8*)hp;
      b2l[nt] = *(const bf16x8*)(hp + 64 * 136);
    }
#pragma unroll
    for (int nt = 0; nt < 4; ++nt) {
      acc[nt] = MFMA(ah, b2h[nt], acc[nt], 0, 0, 0);
      acc[nt] = MFMA(al, b2h[nt], acc[nt], 0, 0, 0);
      acc[nt] = MFMA(ah, b2l[nt], acc[nt], 0, 0, 0);
    }
  }
  __syncthreads();

  // stage P tile, coalesced store
  {
    const int f0 = hbase + q * 4;
    const float* bp = &b2e[f0];
#pragma unroll
    for (int nt = 0; nt < 4; ++nt) {
      const int e = nt * 16 + lr;
      bf16x4 o;
#pragma unroll
      for (int r = 0; r < 4; ++r) o[r] = (bf16)(acc[nt][r] + bp[r]);
      *(bf16x4*)&R[e * 136 + f0] = o;
    }
  }
  __syncthreads();
#pragma unroll
  for (int it = 0; it < 2; ++it) {
    const int idx = it * 512 + tid;
    const int row = idx >> 4;
    const int f8 = (idx & 15) * 8;
    const int n = n0 + row;
    if (n < N)
      *(bf16x8*)&Pout[(size_t)n * 128 + f8] = *(const bf16x8*)&R[row * 136 + f8];
  }
}

// ---------------- UW = u @ W1c + b1 (layer 0 only) -----------------------
__global__ void uw_kernel(const float* __restrict__ u, const float* __restrict__ w1,
                          const float* __restrict__ b1, float* __restrict__ UW) {
  const int b = blockIdx.x, h = threadIdx.x;
  float s = b1[h];
#pragma unroll 8
  for (int k = 0; k < 128; ++k)
    s = fmaf(u[b * 128 + k], w1[(size_t)(256 + k) * 128 + h], s);
  UW[b * 128 + h] = s;
}

// ---------------- global MLP + fused UW for next layer -------------------
__global__ __launch_bounds__(128)
void gmlp_kernel(const float* __restrict__ uin, float* __restrict__ gx,
                 const int* __restrict__ gcnt,
                 const float* __restrict__ gw1, const float* __restrict__ gb1,
                 const float* __restrict__ gw2, const float* __restrict__ gb2,
                 float* __restrict__ uout,
                 const float* __restrict__ w1n_next,
                 const float* __restrict__ b1n_next,
                 float* __restrict__ UW, int has_next) {
  __shared__ float g[256];
  __shared__ float g1[128];
  const int b = blockIdx.x;
  const int t = threadIdx.x;
  const int c = gcnt[b];
  const float inv = 1.f / (float)(c > 1 ? c : 1);
  g[t] = uin[b * 128 + t];
  g[128 + t] = gx[b * 128 + t] * inv;
  gx[b * 128 + t] = 0.f;
  __syncthreads();
  float acc = gb1[t];
#pragma unroll 8
  for (int k = 0; k < 256; ++k) acc = fmaf(g[k], gw1[k * 128 + t], acc);
  g1[t] = fmaxf(acc, 0.f);
  __syncthreads();
  float acc2 = gb2[t];
#pragma unroll 8
  for (int k = 0; k < 128; ++k) acc2 = fmaf(g1[k], gw2[k * 128 + t], acc2);
  uout[b * 128 + t] = acc2;
  if (has_next) {
    __syncthreads();
    g[t] = acc2;
    __syncthreads();
    float s = b1n_next[t];
#pragma unroll 8
    for (int k = 0; k < 128; ++k)
      s = fmaf(g[k], w1n_next[(size_t)(256 + k) * 128 + t], s);
    UW[b * 128 + t] = s;
  }
}

// ---------------- host ----------------
extern "C" void kernel_launch(void* const* d_in, const int* in_sizes, int n_in,
                              void* d_out, int out_size, void* d_ws, size_t ws_size,
                              hipStream_t stream) {
  constexpr int N = 50000, E = 600000, B = 64, F = 128, L = 4;

  const float* x0    = (const float*)d_in[0];
  const int*   ei    = (const int*)  d_in[1];
  const float* u0    = (const float*)d_in[2];
  const int*   batch = (const int*)  d_in[3];
  const float* n1w1  = (const float*)d_in[4];
  const float* n1b1  = (const float*)d_in[5];
  const float* n1w2  = (const float*)d_in[6];
  const float* n1b2  = (const float*)d_in[7];
  const float* n2w1  = (const float*)d_in[8];
  const float* n2b1  = (const float*)d_in[9];
  const float* n2w2  = (const float*)d_in[10];
  const float* n2b2  = (const float*)d_in[11];
  const float* gw1   = (const float*)d_in[12];
  const float* gb1   = (const float*)d_in[13];
  const float* gw2   = (const float*)d_in[14];
  const float* gb2   = (const float*)d_in[15];
  float* out = (float*)d_out;

  char* p = (char*)d_ws;
  auto carve = [&](size_t bytes) -> void* {
    void* q = (void*)p;
    p += (bytes + 255) & ~(size_t)255;
    return q;
  };
  float* ubuf  = (float*)carve((size_t)B * F * 4);
  float* gx    = (float*)carve((size_t)B * F * 4);
  float* UW    = (float*)carve((size_t)B * F * 4);
  int*   cnt   = (int*)carve((size_t)N * 4);
  int*   colptr= (int*)carve((size_t)(N + 1) * 4);
  int*   rctr  = (int*)carve((size_t)N * 4);
  int*   gcnt  = (int*)carve((size_t)B * 4);
  int*   btot  = (int*)carve(32 * 4);
  int*   esrow = (int*)carve((size_t)E * 4);
  bf16*  xhi   = (bf16*)carve((size_t)N * F * 2);
  bf16*  xlo   = (bf16*)carve((size_t)N * F * 2);
  bf16*  P_a   = (bf16*)carve((size_t)N * F * 2);
  bf16*  P_b   = (bf16*)carve((size_t)N * F * 2);
  bf16*  aggh  = (bf16*)carve((size_t)N * F * 2);
  bf16*  aggl  = (bf16*)carve((size_t)N * F * 2);
  bf16*  w1t_e = (bf16*)carve((size_t)L * 2 * 128 * 128 * 2);
  bf16*  w2t_e = (bf16*)carve((size_t)L * 2 * 128 * 128 * 2);
  bf16*  w1t_n = (bf16*)carve((size_t)L * 2 * 256 * 128 * 2);
  bf16*  w2t_n = (bf16*)carve((size_t)L * 2 * 128 * 128 * 2);

  constexpr int SCAN_BLOCKS = (N + 2047) / 2048;

  hipMemsetAsync(cnt, 0, (size_t)N * 4, stream);
  hipMemsetAsync(gx, 0, (size_t)B * F * 4, stream);   // re-zeroed by gmlp
  hist_kernel<<<(E + 255) / 256, 256, 0, stream>>>(ei, cnt, E);
  gcnt_kernel<<<1, 64, 0, stream>>>(batch, gcnt, N, B);
  scan1_kernel<<<SCAN_BLOCKS, 256, 0, stream>>>(cnt, colptr, rctr, btot, N);
  scan2_kernel<<<SCAN_BLOCKS, 256, 0, stream>>>(colptr, rctr, btot, N);
  place_kernel<<<(E + 255) / 256, 256, 0, stream>>>(ei, rctr, esrow, E);
  wsplit_kernel<<<dim3(64, L), 256, 0, stream>>>(n1w1, w1t_e, 128, 128, 128);
  wsplit_kernel<<<dim3(64, L), 256, 0, stream>>>(n1w2, w2t_e, 128, 128, 128);
  wsplit_kernel<<<dim3(128, L), 256, 0, stream>>>(n2w1, w1t_n, 384, 256, 128);
  wsplit_kernel<<<dim3(64, L), 256, 0, stream>>>(n2w2, w2t_n, 128, 128, 128);
  xsplit_kernel<<<(N * F / 4 + 255) / 256, 256, 0, stream>>>(x0, xhi, xlo, N * F / 4);
  uw_kernel<<<B, 128, 0, stream>>>(u0, n2w1, n2b1, UW);

  const int NB = (N + 63) / 64;
  pnode_mfma<<<NB, 512, 0, stream>>>(xhi, xlo, w1t_e, n1b1, w2t_e, n1b2, P_a, N);

  for (int l = 0; l < L; ++l) {
    const float* uin  = l ? ubuf : u0;
    float*       uout = (l == L - 1) ? out + (size_t)N * F : ubuf;
    const int    wx   = (l == L - 1) ? 1 : 0;
    const int    hn   = (l < L - 1) ? 1 : 0;
    const bf16*  Pin  = (l & 1) ? P_b : P_a;
    bf16*        Pout = (l & 1) ? P_a : P_b;
    const int    le   = hn ? (l + 1) : l;

    agg_csr<<<(N + 3) / 4, 256, 0, stream>>>(Pin, colptr, esrow, aggh, aggl, N, E);
    node_p<<<NB, 512, 0, stream>>>(
        xhi, xlo, aggh, aggl, UW, batch,
        w1t_n + (size_t)l * 65536, w2t_n + (size_t)l * 32768,
        n2b2 + l * 128,
        w1t_e + (size_t)le * 32768, n1b1 + le * 128,
        w2t_e + (size_t)le * 32768, n1b2 + le * 128,
        Pout, gx, out, wx, hn, N);
    gmlp_kernel<<<B, 128, 0, stream>>>(
        uin, gx, gcnt,
        gw1 + (size_t)l * 256 * 128, gb1 + l * 128,
        gw2 + (size_t)l * 128 * 128, gb2 + l * 128, uout,
        hn ? (n2w1 + (size_t)(l + 1) * 384 * 128) : n2w1,
        hn ? (n2b1 + (l + 1) * 128) : n2b1,
        UW, hn);
  }
}

// Round 10
// 708.093 us; speedup vs baseline: 1.1708x; 1.1708x over previous
//
#include <hip/hip_runtime.h>

typedef __bf16 bf16;
typedef bf16 bf16x8 __attribute__((ext_vector_type(8)));
typedef bf16 bf16x4 __attribute__((ext_vector_type(4)));
typedef bf16 bf16x2 __attribute__((ext_vector_type(2)));
typedef float floatx4 __attribute__((ext_vector_type(4)));

#define MFMA __builtin_amdgcn_mfma_f32_16x16x32_bf16

__device__ __forceinline__ float bfhi_f(unsigned u) {
  const unsigned x = u << 16;
  return __builtin_bit_cast(float, x);
}
__device__ __forceinline__ float bflo_f(unsigned u) {
  const unsigned x = u & 0xffff0000u;
  return __builtin_bit_cast(float, x);
}

// ---------------- setup kernels ----------------

__global__ void hist_kernel(const int* __restrict__ ei, int* __restrict__ cnt, int E) {
  int e = blockIdx.x * blockDim.x + threadIdx.x;
  if (e < E) atomicAdd(&cnt[ei[E + e]], 1);
}

__global__ void gcnt_kernel(const int* __restrict__ batch, int* __restrict__ gcnt,
                            int N, int B) {
  const int b = threadIdx.x;
  if (b >= B) return;
  auto lb = [&](int v) {
    int lo = 0, hi = N;
    while (lo < hi) {
      const int mid = (lo + hi) >> 1;
      if (batch[mid] < v) lo = mid + 1; else hi = mid;
    }
    return lo;
  };
  gcnt[b] = lb(b + 1) - lb(b);
}

__global__ void scan1_kernel(const int* __restrict__ cnt, int* __restrict__ colptr,
                             int* __restrict__ rctr, int* __restrict__ btot, int n) {
  __shared__ int sd[256];
  const int tid = threadIdx.x;
  const int i0 = blockIdx.x * 2048 + tid * 8;
  int v[8];
  int tot = 0;
#pragma unroll
  for (int j = 0; j < 8; ++j) {
    const int i = i0 + j;
    v[j] = (i < n) ? cnt[i] : 0;
    tot += v[j];
  }
  sd[tid] = tot;
  __syncthreads();
  for (int off = 1; off < 256; off <<= 1) {
    const int t = (tid >= off) ? sd[tid - off] : 0;
    __syncthreads();
    sd[tid] += t;
    __syncthreads();
  }
  int excl = sd[tid] - tot;
#pragma unroll
  for (int j = 0; j < 8; ++j) {
    const int i = i0 + j;
    if (i < n) { colptr[i] = excl; rctr[i] = excl; }
    excl += v[j];
  }
  if (tid == 255) btot[blockIdx.x] = sd[255];
}

__global__ void scan2_kernel(int* __restrict__ colptr, int* __restrict__ rctr,
                             const int* __restrict__ btot, int n) {
  __shared__ int off_s;
  const int tid = threadIdx.x;
  if (blockIdx.x == 0) return;
  if (tid == 0) {
    int o = 0;
    for (int j = 0; j < (int)blockIdx.x; ++j) o += btot[j];
    off_s = o;
  }
  __syncthreads();
  const int off = off_s;
  const int i0 = blockIdx.x * 2048 + tid * 8;
#pragma unroll
  for (int j = 0; j < 8; ++j) {
    const int i = i0 + j;
    if (i < n) { colptr[i] += off; rctr[i] += off; }
  }
}

__global__ void place_kernel(const int* __restrict__ ei, int* __restrict__ rctr,
                             int* __restrict__ esrow, int E) {
  int e = blockIdx.x * blockDim.x + threadIdx.x;
  if (e >= E) return;
  const int r = ei[e];
  const int c = ei[E + e];
  const int p = atomicAdd(&rctr[c], 1);
  esrow[p] = r;
}

// transpose+split: src [L][Ksrc][H] fp32 (first K rows) -> dst [L][2][H][K] bf16
__global__ void wsplit_kernel(const float* __restrict__ src, bf16* __restrict__ dst,
                              int Ksrc, int K, int HH) {
  const int l = blockIdx.y;
  const int gid = blockIdx.x * blockDim.x + threadIdx.x;
  if (gid >= K * HH) return;
  const int h = gid / K, k = gid - h * K;
  const float v = src[(size_t)l * Ksrc * HH + (size_t)k * HH + h];
  const bf16 hi = (bf16)v;
  const bf16 lo = (bf16)(v - (float)hi);
  bf16* d = dst + (size_t)l * 2 * K * HH;
  d[(size_t)h * K + k] = hi;
  d[(size_t)K * HH + (size_t)h * K + k] = lo;
}

__global__ void xsplit_kernel(const float* __restrict__ x, bf16* __restrict__ xhi,
                              bf16* __restrict__ xlo, int n4) {
  const int i = blockIdx.x * 256 + threadIdx.x;
  if (i >= n4) return;
  const float4 v = ((const float4*)x)[i];
  bf16x4 h, l;
  const float vv[4] = {v.x, v.y, v.z, v.w};
#pragma unroll
  for (int r = 0; r < 4; ++r) {
    h[r] = (bf16)vv[r];
    l[r] = (bf16)(vv[r] - (float)h[r]);
  }
  *(bf16x4*)&xhi[(size_t)i * 4] = h;
  *(bf16x4*)&xlo[(size_t)i * 4] = l;
}

// ---------------- layer-0 edge MLP per node (R8 4-wave version) ----------
__global__ __launch_bounds__(256, 4)
void pnode_mfma(const bf16* __restrict__ xh, const bf16* __restrict__ xl,
                const bf16* __restrict__ w1t, const float* __restrict__ b1,
                const bf16* __restrict__ w2t, const float* __restrict__ b2,
                bf16* __restrict__ P, int N) {
  __shared__ __align__(16) bf16 R[2 * 64 * 136];

  const int tid = threadIdx.x;
  const int n0 = blockIdx.x * 64;
  const int wave = tid >> 6, lane = tid & 63, q = lane >> 4, lr = lane & 15;
  const int hbase = wave * 32;

  int nn[4];
#pragma unroll
  for (int nt = 0; nt < 4; ++nt) {
    int n = n0 + nt * 16 + lr;
    nn[nt] = (n > N - 1) ? (N - 1) : n;
  }

  const floatx4 zz = {0.f, 0.f, 0.f, 0.f};
  floatx4 acc[2][4];
#pragma unroll
  for (int mt = 0; mt < 2; ++mt)
#pragma unroll
    for (int nt = 0; nt < 4; ++nt) acc[mt][nt] = zz;

  // GEMM1: K=128, B dbuf
  {
    bf16x8 bh[2][4], bl[2][4];
#pragma unroll
    for (int nt = 0; nt < 4; ++nt) {
      const size_t off = (size_t)nn[nt] * 128 + q * 8;
      bh[0][nt] = *(const bf16x8*)(xh + off);
      bl[0][nt] = *(const bf16x8*)(xl + off);
    }
#pragma unroll
    for (int kc = 0; kc < 4; ++kc) {
      const int cur = kc & 1, nxt = cur ^ 1;
      if (kc < 3) {
#pragma unroll
        for (int nt = 0; nt < 4; ++nt) {
          const size_t off = (size_t)nn[nt] * 128 + (kc + 1) * 32 + q * 8;
          bh[nxt][nt] = *(const bf16x8*)(xh + off);
          bl[nxt][nt] = *(const bf16x8*)(xl + off);
        }
      }
      bf16x8 ah[2], al[2];
#pragma unroll
      for (int mt = 0; mt < 2; ++mt) {
        const bf16* wp = w1t + (size_t)(hbase + mt * 16 + lr) * 128 + kc * 32 + q * 8;
        ah[mt] = *(const bf16x8*)wp;
        al[mt] = *(const bf16x8*)(wp + 16384);
      }
#pragma unroll
      for (int nt = 0; nt < 4; ++nt)
#pragma unroll
        for (int mt = 0; mt < 2; ++mt) {
          acc[mt][nt] = MFMA(ah[mt], bh[cur][nt], acc[mt][nt], 0, 0, 0);
          acc[mt][nt] = MFMA(al[mt], bh[cur][nt], acc[mt][nt], 0, 0, 0);
          acc[mt][nt] = MFMA(ah[mt], bl[cur][nt], acc[mt][nt], 0, 0, 0);
        }
    }
  }

  // epilogue 1: bias+relu -> H1 hi/lo
#pragma unroll
  for (int mt = 0; mt < 2; ++mt) {
    const int h0 = hbase + mt * 16 + q * 4;
    const float* bp = &b1[h0];
#pragma unroll
    for (int nt = 0; nt < 4; ++nt) {
      const int e = nt * 16 + lr;
      bf16x4 hh, ll;
#pragma unroll
      for (int r = 0; r < 4; ++r) {
        const float v = fmaxf(acc[mt][nt][r] + bp[r], 0.f);
        hh[r] = (bf16)v;
        ll[r] = (bf16)(v - (float)hh[r]);
      }
      *(bf16x4*)&R[e * 136 + h0] = hh;
      *(bf16x4*)&R[64 * 136 + e * 136 + h0] = ll;
      acc[mt][nt] = zz;
    }
  }
  __syncthreads();

  // GEMM2
#pragma unroll
  for (int ks = 0; ks < 4; ++ks) {
    bf16x8 ah[2], al[2], b2h[4], b2l[4];
#pragma unroll
    for (int mt = 0; mt < 2; ++mt) {
      const bf16* wp = w2t + (size_t)(hbase + mt * 16 + lr) * 128 + ks * 32 + q * 8;
      ah[mt] = *(const bf16x8*)wp;
      al[mt] = *(const bf16x8*)(wp + 16384);
    }
#pragma unroll
    for (int nt = 0; nt < 4; ++nt) {
      const bf16* hp = &R[(nt * 16 + lr) * 136 + ks * 32 + q * 8];
      b2h[nt] = *(const bf16x8*)hp;
      b2l[nt] = *(const bf16x8*)(hp + 64 * 136);
    }
#pragma unroll
    for (int nt = 0; nt < 4; ++nt)
#pragma unroll
      for (int mt = 0; mt < 2; ++mt) {
        acc[mt][nt] = MFMA(ah[mt], b2h[nt], acc[mt][nt], 0, 0, 0);
        acc[mt][nt] = MFMA(al[mt], b2h[nt], acc[mt][nt], 0, 0, 0);
        acc[mt][nt] = MFMA(ah[mt], b2l[nt], acc[mt][nt], 0, 0, 0);
      }
  }
  __syncthreads();

  // epilogue 2: +b2 -> tile in LDS, coalesced store
#pragma unroll
  for (int mt = 0; mt < 2; ++mt) {
    const int f0 = hbase + mt * 16 + q * 4;
    const float* bp = &b2[f0];
#pragma unroll
    for (int nt = 0; nt < 4; ++nt) {
      const int e = nt * 16 + lr;
      bf16x4 o;
#pragma unroll
      for (int r = 0; r < 4; ++r) o[r] = (bf16)(acc[mt][nt][r] + bp[r]);
      *(bf16x4*)&R[e * 136 + f0] = o;
    }
  }
  __syncthreads();
#pragma unroll
  for (int it = 0; it < 4; ++it) {
    const int idx = it * 256 + tid;
    const int row = idx >> 4;
    const int f8 = (idx & 15) * 8;
    const int n = n0 + row;
    if (n < N)
      *(bf16x8*)&P[(size_t)n * 128 + f8] = *(const bf16x8*)&R[row * 136 + f8];
  }
}

// ---------------- CSR mean-aggregate (R9 wave-per-column, bf16x2/lane) ---
__global__ __launch_bounds__(256, 8)
void agg_csr(const bf16* __restrict__ P, const int* __restrict__ colptr,
             const int* __restrict__ esrow,
             bf16* __restrict__ aggh, bf16* __restrict__ aggl, int N, int E) {
  const int lane = threadIdx.x & 63;
  const int c = blockIdx.x * 4 + (threadIdx.x >> 6);
  if (c >= N) return;
  const int beg = colptr[c];
  const int end = (c == N - 1) ? E : colptr[c + 1];
  float s0[4] = {0.f, 0.f, 0.f, 0.f};
  float s1[4] = {0.f, 0.f, 0.f, 0.f};
  int e = beg;
  for (; e + 8 <= end; e += 8) {
    int r[8];
#pragma unroll
    for (int j = 0; j < 8; ++j) r[j] = esrow[e + j];
    unsigned v[8];
#pragma unroll
    for (int j = 0; j < 8; ++j)
      v[j] = *(const unsigned*)&P[(size_t)r[j] * 128 + lane * 2];
#pragma unroll
    for (int j = 0; j < 8; ++j) {
      s0[j & 3] += bfhi_f(v[j]);
      s1[j & 3] += bflo_f(v[j]);
    }
  }
  const int rem = end - e;
  if (rem > 0) {
    int r[8];
#pragma unroll
    for (int j = 0; j < 8; ++j) r[j] = esrow[e + (j < rem ? j : 0)];
    unsigned v[8];
#pragma unroll
    for (int j = 0; j < 8; ++j)
      v[j] = *(const unsigned*)&P[(size_t)r[j] * 128 + lane * 2];
#pragma unroll
    for (int j = 0; j < 8; ++j) {
      if (j < rem) {
        s0[j & 3] += bfhi_f(v[j]);
        s1[j & 3] += bflo_f(v[j]);
      }
    }
  }
  const int cc = end - beg;
  const float inv = 1.f / (float)(cc > 1 ? cc : 1);
  const float v0 = ((s0[0] + s0[1]) + (s0[2] + s0[3])) * inv;
  const float v1 = ((s1[0] + s1[1]) + (s1[2] + s1[3])) * inv;
  bf16x2 h, l;
  h[0] = (bf16)v0;  l[0] = (bf16)(v0 - (float)h[0]);
  h[1] = (bf16)v1;  l[1] = (bf16)(v1 - (float)h[1]);
  *(bf16x2*)&aggh[(size_t)c * 128 + lane * 2] = h;
  *(bf16x2*)&aggl[(size_t)c * 128 + lane * 2] = l;
}

// ---------------- fused node MLP + gsum + next-layer P (R8 4-wave) -------
__global__ __launch_bounds__(256, 4)
void node_p(bf16* xh, bf16* xl,
            const bf16* __restrict__ aggh, const bf16* __restrict__ aggl,
            const float* __restrict__ UW, const int* __restrict__ batch,
            const bf16* __restrict__ w1t, const bf16* __restrict__ w2t,
            const float* __restrict__ b2,
            const bf16* __restrict__ w1te, const float* __restrict__ b1e,
            const bf16* __restrict__ w2te, const float* __restrict__ b2e,
            bf16* __restrict__ Pout, float* __restrict__ gx,
            float* __restrict__ xout, int write_x, int has_next, int N) {
  __shared__ __align__(16) bf16 R[2 * 64 * 136];   // 34.8 KB, time-shared
  __shared__ int sbatch[64];

  const int tid = threadIdx.x;
  const int n0 = blockIdx.x * 64;
  const int wave = tid >> 6, lane = tid & 63, q = lane >> 4, lr = lane & 15;
  const int hbase = wave * 32;

  if (tid < 64) {
    int n = n0 + tid;
    sbatch[tid] = batch[(n > N - 1) ? (N - 1) : n];
  }

  int nn[4], ub[4];
#pragma unroll
  for (int nt = 0; nt < 4; ++nt) {
    int n = n0 + nt * 16 + lr;
    if (n > N - 1) n = N - 1;
    nn[nt] = n;
    ub[nt] = batch[n];
  }

  floatx4 acc[2][4];
#pragma unroll
  for (int mt = 0; mt < 2; ++mt)
#pragma unroll
    for (int nt = 0; nt < 4; ++nt)
      acc[mt][nt] = *(const floatx4*)&UW[(size_t)ub[nt] * 128 + hbase + mt * 16 + q * 4];

  // GEMM1: K=256 (x hi/lo | agg hi/lo), B double-buffered from global
  {
    bf16x8 bh[2][4], bl[2][4];
    auto loadB = [&](int kc, int buf) {
#pragma unroll
      for (int nt = 0; nt < 4; ++nt) {
        if (kc < 4) {
          const size_t off = (size_t)nn[nt] * 128 + kc * 32 + q * 8;
          bh[buf][nt] = *(const bf16x8*)(xh + off);
          bl[buf][nt] = *(const bf16x8*)(xl + off);
        } else {
          const size_t off = (size_t)nn[nt] * 128 + (kc - 4) * 32 + q * 8;
          bh[buf][nt] = *(const bf16x8*)(aggh + off);
          bl[buf][nt] = *(const bf16x8*)(aggl + off);
        }
      }
    };
    loadB(0, 0);
#pragma unroll
    for (int kc = 0; kc < 8; ++kc) {
      const int cur = kc & 1, nxt = cur ^ 1;
      if (kc < 7) loadB(kc + 1, nxt);
      bf16x8 ah[2], al[2];
#pragma unroll
      for (int mt = 0; mt < 2; ++mt) {
        const bf16* wp = w1t + (size_t)(hbase + mt * 16 + lr) * 256 + kc * 32 + q * 8;
        ah[mt] = *(const bf16x8*)wp;
        al[mt] = *(const bf16x8*)(wp + 32768);
      }
#pragma unroll
      for (int nt = 0; nt < 4; ++nt)
#pragma unroll
        for (int mt = 0; mt < 2; ++mt) {
          acc[mt][nt] = MFMA(ah[mt], bh[cur][nt], acc[mt][nt], 0, 0, 0);
          acc[mt][nt] = MFMA(al[mt], bh[cur][nt], acc[mt][nt], 0, 0, 0);
          acc[mt][nt] = MFMA(ah[mt], bl[cur][nt], acc[mt][nt], 0, 0, 0);
        }
    }
  }

  // epilogue 1: relu (b1 folded in UW) -> H1 hi/lo
  const floatx4 zz = {0.f, 0.f, 0.f, 0.f};
#pragma unroll
  for (int mt = 0; mt < 2; ++mt) {
    const int h0 = hbase + mt * 16 + q * 4;
#pragma unroll
    for (int nt = 0; nt < 4; ++nt) {
      const int e = nt * 16 + lr;
      bf16x4 hh, ll;
#pragma unroll
      for (int r = 0; r < 4; ++r) {
        const float v = fmaxf(acc[mt][nt][r], 0.f);
        hh[r] = (bf16)v;
        ll[r] = (bf16)(v - (float)hh[r]);
      }
      *(bf16x4*)&R[e * 136 + h0] = hh;
      *(bf16x4*)&R[64 * 136 + e * 136 + h0] = ll;
      acc[mt][nt] = zz;
    }
  }
  __syncthreads();

  // GEMM2
#pragma unroll
  for (int ks = 0; ks < 4; ++ks) {
    bf16x8 ah[2], al[2], b2h[4], b2l[4];
#pragma unroll
    for (int mt = 0; mt < 2; ++mt) {
      const bf16* wp = w2t + (size_t)(hbase + mt * 16 + lr) * 128 + ks * 32 + q * 8;
      ah[mt] = *(const bf16x8*)wp;
      al[mt] = *(const bf16x8*)(wp + 16384);
    }
#pragma unroll
    for (int nt = 0; nt < 4; ++nt) {
      const bf16* hp = &R[(nt * 16 + lr) * 136 + ks * 32 + q * 8];
      b2h[nt] = *(const bf16x8*)hp;
      b2l[nt] = *(const bf16x8*)(hp + 64 * 136);
    }
#pragma unroll
    for (int nt = 0; nt < 4; ++nt)
#pragma unroll
      for (int mt = 0; mt < 2; ++mt) {
        acc[mt][nt] = MFMA(ah[mt], b2h[nt], acc[mt][nt], 0, 0, 0);
        acc[mt][nt] = MFMA(al[mt], b2h[nt], acc[mt][nt], 0, 0, 0);
        acc[mt][nt] = MFMA(ah[mt], b2l[nt], acc[mt][nt], 0, 0, 0);
      }
  }
  __syncthreads();   // H1 reads done; Xt fp32 [64][132] overlays R

  // epilogue 2: +b2 -> Xt
  float* Xt = (float*)&R[0];
#pragma unroll
  for (int mt = 0; mt < 2; ++mt) {
    const int f0 = hbase + mt * 16 + q * 4;
    const float* bp = &b2[f0];
#pragma unroll
    for (int nt = 0; nt < 4; ++nt) {
      const int e = nt * 16 + lr;
      const int n = n0 + e;
      float4 o;
      o.x = (n < N) ? acc[mt][nt][0] + bp[0] : 0.f;
      o.y = (n < N) ? acc[mt][nt][1] + bp[1] : 0.f;
      o.z = (n < N) ? acc[mt][nt][2] + bp[2] : 0.f;
      o.w = (n < N) ? acc[mt][nt][3] + bp[3] : 0.f;
      *(float4*)&Xt[e * 132 + f0] = o;
    }
  }
  __syncthreads();

  // coalesced xh/xl stores (next layer), optional xout
  if (has_next) {
#pragma unroll
    for (int it = 0; it < 4; ++it) {
      const int idx = it * 256 + tid;
      const int row = idx >> 4;
      const int f8 = (idx & 15) * 8;
      const int n = n0 + row;
      if (n < N) {
        bf16x8 hh, ll;
#pragma unroll
        for (int j = 0; j < 8; ++j) {
          const float v = Xt[row * 132 + f8 + j];
          hh[j] = (bf16)v;
          ll[j] = (bf16)(v - (float)hh[j]);
        }
        *(bf16x8*)&xh[(size_t)n * 128 + f8] = hh;
        *(bf16x8*)&xl[(size_t)n * 128 + f8] = ll;
      }
    }
  }
  if (write_x) {
#pragma unroll
    for (int it = 0; it < 8; ++it) {
      const int idx = it * 256 + tid;
      const int row = idx >> 5;
      const int f4 = (idx & 31) * 4;
      const int n = n0 + row;
      if (n < N)
        *(float4*)&xout[(size_t)n * 128 + f4] = *(const float4*)&Xt[row * 132 + f4];
    }
  }

  // fused gsum: segmented reduce over 64 sorted-batch nodes
  {
    const int f = tid & 127;
    const int es = (tid >> 7) * 32;
    int cur = sbatch[es];
    float s = 0.f;
    for (int e = es; e < es + 32; ++e) {
      const int b = sbatch[e];
      const float v = Xt[e * 132 + f];
      if (b != cur) {
        atomicAdd(&gx[(size_t)cur * 128 + f], s);
        s = 0.f;
        cur = b;
      }
      s += v;
    }
    atomicAdd(&gx[(size_t)cur * 128 + f], s);
  }

  if (!has_next) return;

  // P phase: Pout = relu(x@W1e+b1e)@W2e+b2e, x from Xt in LDS
#pragma unroll
  for (int mt = 0; mt < 2; ++mt)
#pragma unroll
    for (int nt = 0; nt < 4; ++nt) acc[mt][nt] = zz;

#pragma unroll
  for (int kc = 0; kc < 4; ++kc) {
    bf16x8 ah[2], al[2], bh[4], bl[4];
#pragma unroll
    for (int mt = 0; mt < 2; ++mt) {
      const bf16* wp = w1te + (size_t)(hbase + mt * 16 + lr) * 128 + kc * 32 + q * 8;
      ah[mt] = *(const bf16x8*)wp;
      al[mt] = *(const bf16x8*)(wp + 16384);
    }
#pragma unroll
    for (int nt = 0; nt < 4; ++nt) {
      const float* xp = &Xt[(nt * 16 + lr) * 132 + kc * 32 + q * 8];
#pragma unroll
      for (int r = 0; r < 8; ++r) {
        const float v = xp[r];
        bh[nt][r] = (bf16)v;
        bl[nt][r] = (bf16)(v - (float)bh[nt][r]);
      }
    }
#pragma unroll
    for (int nt = 0; nt < 4; ++nt)
#pragma unroll
      for (int mt = 0; mt < 2; ++mt) {
        acc[mt][nt] = MFMA(ah[mt], bh[nt], acc[mt][nt], 0, 0, 0);
        acc[mt][nt] = MFMA(al[mt], bh[nt], acc[mt][nt], 0, 0, 0);
        acc[mt][nt] = MFMA(ah[mt], bl[nt], acc[mt][nt], 0, 0, 0);
      }
  }
  __syncthreads();   // Xt reads (incl. gsum) done; H1p overlays R

  // epilogue 1p: +b1e, relu -> H1p hi/lo
#pragma unroll
  for (int mt = 0; mt < 2; ++mt) {
    const int h0 = hbase + mt * 16 + q * 4;
    const float* bp = &b1e[h0];
#pragma unroll
    for (int nt = 0; nt < 4; ++nt) {
      const int e = nt * 16 + lr;
      bf16x4 hh, ll;
#pragma unroll
      for (int r = 0; r < 4; ++r) {
        const float v = fmaxf(acc[mt][nt][r] + bp[r], 0.f);
        hh[r] = (bf16)v;
        ll[r] = (bf16)(v - (float)hh[r]);
      }
      *(bf16x4*)&R[e * 136 + h0] = hh;
      *(bf16x4*)&R[64 * 136 + e * 136 + h0] = ll;
      acc[mt][nt] = zz;
    }
  }
  __syncthreads();

  // P-GEMM2
#pragma unroll
  for (int ks = 0; ks < 4; ++ks) {
    bf16x8 ah[2], al[2], b2h[4], b2l[4];
#pragma unroll
    for (int mt = 0; mt < 2; ++mt) {
      const bf16* wp = w2te + (size_t)(hbase + mt * 16 + lr) * 128 + ks * 32 + q * 8;
      ah[mt] = *(const bf16x8*)wp;
      al[mt] = *(const bf16x8*)(wp + 16384);
    }
#pragma unroll
    for (int nt = 0; nt < 4; ++nt) {
      const bf16* hp = &R[(nt * 16 + lr) * 136 + ks * 32 + q * 8];
      b2h[nt] = *(const bf16x8*)hp;
      b2l[nt] = *(const bf16x8*)(hp + 64 * 136);
    }
#pragma unroll
    for (int nt = 0; nt < 4; ++nt)
#pragma unroll
      for (int mt = 0; mt < 2; ++mt) {
        acc[mt][nt] = MFMA(ah[mt], b2h[nt], acc[mt][nt], 0, 0, 0);
        acc[mt][nt] = MFMA(al[mt], b2h[nt], acc[mt][nt], 0, 0, 0);
        acc[mt][nt] = MFMA(ah[mt], b2l[nt], acc[mt][nt], 0, 0, 0);
      }
  }
  __syncthreads();

  // stage P tile, coalesced store
#pragma unroll
  for (int mt = 0; mt < 2; ++mt) {
    const int f0 = hbase + mt * 16 + q * 4;
    const float* bp = &b2e[f0];
#pragma unroll
    for (int nt = 0; nt < 4; ++nt) {
      const int e = nt * 16 + lr;
      bf16x4 o;
#pragma unroll
      for (int r = 0; r < 4; ++r) o[r] = (bf16)(acc[mt][nt][r] + bp[r]);
      *(bf16x4*)&R[e * 136 + f0] = o;
    }
  }
  __syncthreads();
#pragma unroll
  for (int it = 0; it < 4; ++it) {
    const int idx = it * 256 + tid;
    const int row = idx >> 4;
    const int f8 = (idx & 15) * 8;
    const int n = n0 + row;
    if (n < N)
      *(bf16x8*)&Pout[(size_t)n * 128 + f8] = *(const bf16x8*)&R[row * 136 + f8];
  }
}

// ---------------- UW = u @ W1c + b1 (layer 0 only) -----------------------
__global__ void uw_kernel(const float* __restrict__ u, const float* __restrict__ w1,
                          const float* __restrict__ b1, float* __restrict__ UW) {
  const int b = blockIdx.x, h = threadIdx.x;
  float s = b1[h];
#pragma unroll 8
  for (int k = 0; k < 128; ++k)
    s = fmaf(u[b * 128 + k], w1[(size_t)(256 + k) * 128 + h], s);
  UW[b * 128 + h] = s;
}

// ---------------- global MLP + fused UW for next layer -------------------
__global__ __launch_bounds__(128)
void gmlp_kernel(const float* __restrict__ uin, float* __restrict__ gx,
                 const int* __restrict__ gcnt,
                 const float* __restrict__ gw1, const float* __restrict__ gb1,
                 const float* __restrict__ gw2, const float* __restrict__ gb2,
                 float* __restrict__ uout,
                 const float* __restrict__ w1n_next,
                 const float* __restrict__ b1n_next,
                 float* __restrict__ UW, int has_next) {
  __shared__ float g[256];
  __shared__ float g1[128];
  const int b = blockIdx.x;
  const int t = threadIdx.x;
  const int c = gcnt[b];
  const float inv = 1.f / (float)(c > 1 ? c : 1);
  g[t] = uin[b * 128 + t];
  g[128 + t] = gx[b * 128 + t] * inv;
  gx[b * 128 + t] = 0.f;
  __syncthreads();
  float acc = gb1[t];
#pragma unroll 8
  for (int k = 0; k < 256; ++k) acc = fmaf(g[k], gw1[k * 128 + t], acc);
  g1[t] = fmaxf(acc, 0.f);
  __syncthreads();
  float acc2 = gb2[t];
#pragma unroll 8
  for (int k = 0; k < 128; ++k) acc2 = fmaf(g1[k], gw2[k * 128 + t], acc2);
  uout[b * 128 + t] = acc2;
  if (has_next) {
    __syncthreads();
    g[t] = acc2;
    __syncthreads();
    float s = b1n_next[t];
#pragma unroll 8
    for (int k = 0; k < 128; ++k)
      s = fmaf(g[k], w1n_next[(size_t)(256 + k) * 128 + t], s);
    UW[b * 128 + t] = s;
  }
}

// ---------------- host ----------------
extern "C" void kernel_launch(void* const* d_in, const int* in_sizes, int n_in,
                              void* d_out, int out_size, void* d_ws, size_t ws_size,
                              hipStream_t stream) {
  constexpr int N = 50000, E = 600000, B = 64, F = 128, L = 4;

  const float* x0    = (const float*)d_in[0];
  const int*   ei    = (const int*)  d_in[1];
  const float* u0    = (const float*)d_in[2];
  const int*   batch = (const int*)  d_in[3];
  const float* n1w1  = (const float*)d_in[4];
  const float* n1b1  = (const float*)d_in[5];
  const float* n1w2  = (const float*)d_in[6];
  const float* n1b2  = (const float*)d_in[7];
  const float* n2w1  = (const float*)d_in[8];
  const float* n2b1  = (const float*)d_in[9];
  const float* n2w2  = (const float*)d_in[10];
  const float* n2b2  = (const float*)d_in[11];
  const float* gw1   = (const float*)d_in[12];
  const float* gb1   = (const float*)d_in[13];
  const float* gw2   = (const float*)d_in[14];
  const float* gb2   = (const float*)d_in[15];
  float* out = (float*)d_out;

  char* p = (char*)d_ws;
  auto carve = [&](size_t bytes) -> void* {
    void* q = (void*)p;
    p += (bytes + 255) & ~(size_t)255;
    return q;
  };
  float* ubuf  = (float*)carve((size_t)B * F * 4);
  float* gx    = (float*)carve((size_t)B * F * 4);
  float* UW    = (float*)carve((size_t)B * F * 4);
  int*   cnt   = (int*)carve((size_t)N * 4);
  int*   colptr= (int*)carve((size_t)(N + 1) * 4);
  int*   rctr  = (int*)carve((size_t)N * 4);
  int*   gcnt  = (int*)carve((size_t)B * 4);
  int*   btot  = (int*)carve(32 * 4);
  int*   esrow = (int*)carve((size_t)E * 4);
  bf16*  xhi   = (bf16*)carve((size_t)N * F * 2);
  bf16*  xlo   = (bf16*)carve((size_t)N * F * 2);
  bf16*  P_a   = (bf16*)carve((size_t)N * F * 2);
  bf16*  P_b   = (bf16*)carve((size_t)N * F * 2);
  bf16*  aggh  = (bf16*)carve((size_t)N * F * 2);
  bf16*  aggl  = (bf16*)carve((size_t)N * F * 2);
  bf16*  w1t_e = (bf16*)carve((size_t)L * 2 * 128 * 128 * 2);
  bf16*  w2t_e = (bf16*)carve((size_t)L * 2 * 128 * 128 * 2);
  bf16*  w1t_n = (bf16*)carve((size_t)L * 2 * 256 * 128 * 2);
  bf16*  w2t_n = (bf16*)carve((size_t)L * 2 * 128 * 128 * 2);

  constexpr int SCAN_BLOCKS = (N + 2047) / 2048;

  hipMemsetAsync(cnt, 0, (size_t)N * 4, stream);
  hipMemsetAsync(gx, 0, (size_t)B * F * 4, stream);   // re-zeroed by gmlp
  hist_kernel<<<(E + 255) / 256, 256, 0, stream>>>(ei, cnt, E);
  gcnt_kernel<<<1, 64, 0, stream>>>(batch, gcnt, N, B);
  scan1_kernel<<<SCAN_BLOCKS, 256, 0, stream>>>(cnt, colptr, rctr, btot, N);
  scan2_kernel<<<SCAN_BLOCKS, 256, 0, stream>>>(colptr, rctr, btot, N);
  place_kernel<<<(E + 255) / 256, 256, 0, stream>>>(ei, rctr, esrow, E);
  wsplit_kernel<<<dim3(64, L), 256, 0, stream>>>(n1w1, w1t_e, 128, 128, 128);
  wsplit_kernel<<<dim3(64, L), 256, 0, stream>>>(n1w2, w2t_e, 128, 128, 128);
  wsplit_kernel<<<dim3(128, L), 256, 0, stream>>>(n2w1, w1t_n, 384, 256, 128);
  wsplit_kernel<<<dim3(64, L), 256, 0, stream>>>(n2w2, w2t_n, 128, 128, 128);
  xsplit_kernel<<<(N * F / 4 + 255) / 256, 256, 0, stream>>>(x0, xhi, xlo, N * F / 4);
  uw_kernel<<<B, 128, 0, stream>>>(u0, n2w1, n2b1, UW);

  const int NB = (N + 63) / 64;
  pnode_mfma<<<NB, 256, 0, stream>>>(xhi, xlo, w1t_e, n1b1, w2t_e, n1b2, P_a, N);

  for (int l = 0; l < L; ++l) {
    const float* uin  = l ? ubuf : u0;
    float*       uout = (l == L - 1) ? out + (size_t)N * F : ubuf;
    const int    wx   = (l == L - 1) ? 1 : 0;
    const int    hn   = (l < L - 1) ? 1 : 0;
    const bf16*  Pin  = (l & 1) ? P_b : P_a;
    bf16*        Pout = (l & 1) ? P_a : P_b;
    const int    le   = hn ? (l + 1) : l;

    agg_csr<<<(N + 3) / 4, 256, 0, stream>>>(Pin, colptr, esrow, aggh, aggl, N, E);
    node_p<<<NB, 256, 0, stream>>>(
        xhi, xlo, aggh, aggl, UW, batch,
        w1t_n + (size_t)l * 65536, w2t_n + (size_t)l * 32768,
        n2b2 + l * 128,
        w1t_e + (size_t)le * 32768, n1b1 + le * 128,
        w2t_e + (size_t)le * 32768, n1b2 + le * 128,
        Pout, gx, out, wx, hn, N);
    gmlp_kernel<<<B, 128, 0, stream>>>(
        uin, gx, gcnt,
        gw1 + (size_t)l * 256 * 128, gb1 + l * 128,
        gw2 + (size_t)l * 128 * 128, gb2 + l * 128, uout,
        hn ? (n2w1 + (size_t)(l + 1) * 384 * 128) : n2w1,
        hn ? (n2b1 + (l + 1) * 128) : n2b1,
        UW, hn);
  }
}